// Round 10
// baseline (106.359 us; speedup 1.0000x reference)
//
#include <hip/hip_runtime.h>
#include <math.h>

#define EMB 512
#define NM 5
#define HID 64
#define NQ 2048
#define NP 256

typedef __attribute__((ext_vector_type(8))) short short8;   // 8 bf16 = 16B
typedef __attribute__((ext_vector_type(4))) short short4s;  // 4 bf16 = 8B
typedef __attribute__((ext_vector_type(4))) float floatx4;
typedef __attribute__((ext_vector_type(4))) float vf4;
typedef __attribute__((ext_vector_type(2))) float vf2;

// ws layout (bytes)
#define A_BY  0u                   // A[m][q][h] f32 (+b1)          2,621,440
#define B_BY  2621440u             // B[m][h/4][p][h%4] f32           327,680
#define WH_BY 2949120u             // W1 hi bf16 [5][64][1024]        655,360
#define WL_BY 3604480u             // W1 lo bf16 [5][64][1024]        655,360
#define QH_BY 4259840u             // Q  hi bf16 [2048][512]        2,097,152
#define PH_BY 6356992u             // P  hi bf16 [256][512]           262,144

#define LST 72                     // LDS row stride in shorts (144B, 16B-aligned)

__device__ inline unsigned short bfr(float f) {            // f32 -> bf16 RNE
    unsigned u = __float_as_uint(f);
    u += 0x7FFFu + ((u >> 16) & 1u);
    return (unsigned short)(u >> 16);
}

// ---------------------------------------------------------------------------
// Kernel 0: one-shot conversion — UNCHANGED (bit-identical bfr math; gemm
// preserves MFMA order -> absmax stays 0.0009765625 exactly).
__global__ __launch_bounds__(256) void cvt_pre(const float* __restrict__ Q,
                                               const float* __restrict__ P,
                                               const float* __restrict__ W1,
                                               short* __restrict__ WHg,
                                               short* __restrict__ WLg,
                                               short* __restrict__ QHg,
                                               short* __restrict__ PHg) {
    int i = blockIdx.x * 256 + threadIdx.x;
    if (i < 81920) {
        float4 v = ((const float4*)W1)[i];
        short4s hi, lo;
#define C1(I, V) { unsigned short h_ = bfr(V); hi[I] = (short)h_; \
    lo[I] = (short)bfr((V) - __uint_as_float(((unsigned)h_) << 16)); }
        C1(0, v.x) C1(1, v.y) C1(2, v.z) C1(3, v.w)
#undef C1
        ((short4s*)WHg)[i] = hi;
        ((short4s*)WLg)[i] = lo;
    } else if (i < 81920 + 262144) {
        int j = i - 81920;
        float4 v = ((const float4*)Q)[j];
        short4s hi;
        hi[0] = (short)bfr(v.x); hi[1] = (short)bfr(v.y);
        hi[2] = (short)bfr(v.z); hi[3] = (short)bfr(v.w);
        ((short4s*)QHg)[j] = hi;
    } else {
        int j = i - 344064;
        float4 v = ((const float4*)P)[j];
        short4s hi;
        hi[0] = (short)bfr(v.x); hi[1] = (short)bfr(v.y);
        hi[2] = (short)bfr(v.z); hi[3] = (short)bfr(v.w);
        ((short4s*)PHg)[j] = hi;
    }
}

// ---------------------------------------------------------------------------
// Kernel 1: MFMA GEMM — gemm_v4 (R6; best measured). UNCHANGED.
__global__ __launch_bounds__(256) void gemm_v4(const short* __restrict__ WHg,
                                               const short* __restrict__ WLg,
                                               const short* __restrict__ QHg,
                                               const short* __restrict__ PHg,
                                               const float* __restrict__ b1,
                                               float* __restrict__ A,
                                               float* __restrict__ Bv) {
    __shared__ short XH[2][16 * LST];
    __shared__ short WH[2][64 * LST];
    __shared__ short WL[2][64 * LST];

    int tid  = threadIdx.x;
    int lane = tid & 63;
    int ht   = tid >> 6;
    int m    = blockIdx.x % 5;
    int rt   = blockIdx.x / 5;           // 0..143
    int r0   = rt * 16;
    bool isQ = rt < 128;

    int wrow = tid >> 3;                 // 0..31  (also rows +32)
    int wg8  = (tid & 7) * 8;            // k offset (shorts) within 64-chunk
    int off  = isQ ? 0 : 512;
    const short* whp0 = WHg + ((size_t)(m * 64 + wrow)) * 1024 + off + wg8;
    const short* whp1 = whp0 + 32 * 1024;
    const short* wlp0 = WLg + ((size_t)(m * 64 + wrow)) * 1024 + off + wg8;
    const short* wlp1 = wlp0 + 32 * 1024;
    bool hasX = tid < 128;
    int xrow  = tid >> 3;                // 0..15 when hasX
    const short* xp = (isQ ? QHg + (size_t)(r0 + xrow) * 512
                           : PHg + (size_t)(r0 - NQ + xrow) * 512) + wg8;

    int arix = (lane & 15) * LST + (lane >> 4) * 8;
    int brix = (ht * 16 + (lane & 15)) * LST + (lane >> 4) * 8;

    floatx4 ac = {0, 0, 0, 0};
    short8 wh0, wh1, wl0, wl1, xh;

    // prologue: chunk 0 -> buf 0
    wh0 = *(const short8*)&whp0[0]; wh1 = *(const short8*)&whp1[0];
    wl0 = *(const short8*)&wlp0[0]; wl1 = *(const short8*)&wlp1[0];
    if (hasX) xh = *(const short8*)&xp[0];
    *(short8*)&WH[0][wrow * LST + wg8] = wh0;
    *(short8*)&WH[0][(wrow + 32) * LST + wg8] = wh1;
    *(short8*)&WL[0][wrow * LST + wg8] = wl0;
    *(short8*)&WL[0][(wrow + 32) * LST + wg8] = wl1;
    if (hasX) *(short8*)&XH[0][xrow * LST + wg8] = xh;

#pragma unroll 1
    for (int c = 0; c < 8; ++c) {
        int cur = c & 1;
        if (c < 7) {                      // issue loads for c+1 (no wait)
            int k0 = (c + 1) * 64;
            wh0 = *(const short8*)&whp0[k0]; wh1 = *(const short8*)&whp1[k0];
            wl0 = *(const short8*)&wlp0[k0]; wl1 = *(const short8*)&wlp1[k0];
            if (hasX) xh = *(const short8*)&xp[k0];
        }
        __syncthreads();

#pragma unroll
        for (int s = 0; s < 2; ++s) {     // two 32-k sub-chunks
            short8 Ah = *(const short8*)&XH[cur][arix + s * 32];
            short8 Bh = *(const short8*)&WH[cur][brix + s * 32];
            short8 Bl = *(const short8*)&WL[cur][brix + s * 32];
            ac = __builtin_amdgcn_mfma_f32_16x16x32_bf16(Ah, Bl, ac, 0, 0, 0);
            ac = __builtin_amdgcn_mfma_f32_16x16x32_bf16(Ah, Bh, ac, 0, 0, 0);
        }

        if (c < 7) {                      // store to next buf
            int nb = cur ^ 1;
            *(short8*)&WH[nb][wrow * LST + wg8] = wh0;
            *(short8*)&WH[nb][(wrow + 32) * LST + wg8] = wh1;
            *(short8*)&WL[nb][wrow * LST + wg8] = wl0;
            *(short8*)&WL[nb][(wrow + 32) * LST + wg8] = wl1;
            if (hasX) *(short8*)&XH[nb][xrow * LST + wg8] = xh;
        }
    }

    int col  = lane & 15;
    int rloc = (lane >> 4) * 4;
    int hh   = ht * 16 + col;
    int rr   = r0 + rloc;

    if (isQ) {
        float bb = b1[m * 64 + hh];
        float* dst = &A[((size_t)m * NQ + rr) * HID + hh];
        dst[0 * HID] = ac.x + bb; dst[1 * HID] = ac.y + bb;
        dst[2 * HID] = ac.z + bb; dst[3 * HID] = ac.w + bb;
    } else {
        int p = rr - NQ;
        float* dst = &Bv[(((size_t)(m * 16 + (hh >> 2))) * NP + p) * 4 + (hh & 3)];
        dst[0 * 4] = ac.x; dst[1 * 4] = ac.y; dst[2 * 4] = ac.z; dst[3 * 4] = ac.w;
    }
}

// ---------------------------------------------------------------------------
// Kernel 2: fused_v7b — ZERO-LDS (R7 design, readfirstlane removed; tid>>6
// is already wave-uniform and the compiler's uniformity analysis scalarizes
// it). lane = p -> B loads 1KB coalesced per wave, no duplication (per-CU
// L1 traffic 320KB); wave = q-pair -> A/W2 rows wave-uniform -> SMEM pipe.
// j-half split keeps transient SGPR use bounded; Bc[8] keeps VGPR ~100 ->
// 4 waves/SIMD at grid 1024 = 4 blocks/CU. Accumulation order identical to
// the verified kernel (j=0..15 sequential, same op sequence).
__global__ __launch_bounds__(256) void fused_main(const float* __restrict__ A,
                                                  const float* __restrict__ Bv,
                                                  const float* __restrict__ W2,
                                                  const float* __restrict__ b2,
                                                  float* __restrict__ out) {
    int tid  = threadIdx.x;
    int lane = tid & 63;
    int wq   = tid >> 6;                                  // wave q-pair 0..3
    int bp   = (blockIdx.x & 3) * 64;                     // p-tile base
    int q0   = (blockIdx.x >> 2) * 8;                     // q-tile base
    int p    = bp + lane;                                 // 0..255
    int qa   = q0 + wq * 2;                               // wave's first q row

    const vf4* Bq = (const vf4*)Bv + p;       // f4 idx (m*16+h4)*NP + p

    float s1[2] = {0.f, 0.f}, s2[2] = {0.f, 0.f};

#pragma unroll 1
    for (int m = 0; m < NM; ++m) {
        float bb = b2[m];                                  // uniform scalar
        const float* A0 = A + ((size_t)m * NQ + qa) * HID;       // uniform
        const float* A1 = A0 + HID;                              // uniform
        const float* Wm = W2 + m * HID;                          // uniform

        vf2 acc0 = {0.f, 0.f}, acc1 = {0.f, 0.f};

#pragma unroll
        for (int jh = 0; jh < 2; ++jh) {
            vf4 Bc[8];
#pragma unroll
            for (int j = 0; j < 8; ++j)
                Bc[j] = Bq[(m * 16 + jh * 8 + j) * NP];

#pragma unroll
            for (int j = 0; j < 8; ++j) {
                int h0 = (jh * 8 + j) * 4;
                vf2 w0 = *(const vf2*)&Wm[h0 + 0];         // uniform -> s_load
                vf2 w1 = *(const vf2*)&Wm[h0 + 2];
                vf2 z  = {0.f, 0.f};
                // q row 0
                vf2 a00 = *(const vf2*)&A0[h0 + 0];        // uniform -> s_load
                vf2 a01 = *(const vf2*)&A0[h0 + 2];
                vf2 t00 = __builtin_elementwise_max(a00 + Bc[j].xy, z);
                vf2 t01 = __builtin_elementwise_max(a01 + Bc[j].zw, z);
                acc0 = t00 * w0 + acc0;                    // v_pk_fma_f32
                acc0 = t01 * w1 + acc0;
                // q row 1
                vf2 a10 = *(const vf2*)&A1[h0 + 0];
                vf2 a11 = *(const vf2*)&A1[h0 + 2];
                vf2 t10 = __builtin_elementwise_max(a10 + Bc[j].xy, z);
                vf2 t11 = __builtin_elementwise_max(a11 + Bc[j].zw, z);
                acc1 = t10 * w0 + acc1;
                acc1 = t11 * w1 + acc1;
            }
        }

        float x0 = acc0.x + acc0.y + bb;
        s1[0] += x0; s2[0] = fmaf(x0, x0, s2[0]);
        float x1 = acc1.x + acc1.y + bb;
        s1[1] += x1; s2[1] = fmaf(x1, x1, s2[1]);
    }

#pragma unroll
    for (int qi = 0; qi < 2; ++qi) {
        float mean = s1[qi] * 0.2f;
        float var  = fmaxf((s2[qi] - s1[qi] * s1[qi] * 0.2f) * 0.25f, 0.f);
        out[(size_t)(qa + qi) * NP + p] = mean * __expf(-sqrtf(var));
    }
}

// ---------------------------------------------------------------------------
extern "C" void kernel_launch(void* const* d_in, const int* in_sizes, int n_in,
                              void* d_out, int out_size, void* d_ws, size_t ws_size,
                              hipStream_t stream) {
    const float* Q  = (const float*)d_in[0];   // (2048, 512)
    const float* P  = (const float*)d_in[1];   // (256, 512)
    const float* W1 = (const float*)d_in[2];   // (5, 64, 1024)
    const float* b1 = (const float*)d_in[3];   // (5, 64)
    const float* W2 = (const float*)d_in[4];   // (5, 64)
    const float* b2 = (const float*)d_in[5];   // (5,)
    float* out = (float*)d_out;

    char*  ws  = (char*)d_ws;
    float* A   = (float*)(ws + A_BY);
    float* B   = (float*)(ws + B_BY);
    short* WHg = (short*)(ws + WH_BY);
    short* WLg = (short*)(ws + WL_BY);
    short* QHg = (short*)(ws + QH_BY);
    short* PHg = (short*)(ws + PH_BY);

    cvt_pre<<<1472, 256, 0, stream>>>(Q, P, W1, WHg, WLg, QHg, PHg);
    gemm_v4<<<720, 256, 0, stream>>>(WHg, WLg, QHg, PHg, b1, A, B);
    fused_main<<<1024, 256, 0, stream>>>(A, B, W2, b2, out);
}

// Round 11
// 93.239 us; speedup vs baseline: 1.1407x; 1.1407x over previous
//
#include <hip/hip_runtime.h>
#include <math.h>

#define EMB 512
#define NM 5
#define HID 64
#define NQ 2048
#define NP 256

typedef __attribute__((ext_vector_type(8))) short short8;   // 8 bf16 = 16B
typedef __attribute__((ext_vector_type(4))) float floatx4;
typedef __attribute__((ext_vector_type(4))) float vf4;      // pk-math vectors
typedef __attribute__((ext_vector_type(2))) float vf2;

// ws layout (bytes)
#define A_BY 0u                    // A[m][q][h] f32 (+b1)   2,621,440
#define B_BY 2621440u              // B[m][h/4][p][h%4] f32    327,680

#define LST 72                     // LDS row stride in shorts (144B, 16B-aligned)

__device__ inline unsigned short bfr(float f) {            // f32 -> bf16 RNE
    unsigned u = __float_as_uint(f);
    u += 0x7FFFu + ((u >> 16) & 1u);
    return (unsigned short)(u >> 16);
}

__device__ inline void cvt8(float4 a, float4 b, short8& hi, short8& lo) {
#define C1(I, V) { unsigned short h_ = bfr(V); hi[I] = (short)h_; \
    lo[I] = (short)bfr(V - __uint_as_float(((unsigned)h_) << 16)); }
    C1(0, a.x) C1(1, a.y) C1(2, a.z) C1(3, a.w)
    C1(4, b.x) C1(5, b.y) C1(6, b.z) C1(7, b.w)
#undef C1
}
__device__ inline void cvt8hi(float4 a, float4 b, short8& hi) {
    hi[0] = (short)bfr(a.x); hi[1] = (short)bfr(a.y);
    hi[2] = (short)bfr(a.z); hi[3] = (short)bfr(a.w);
    hi[4] = (short)bfr(b.x); hi[5] = (short)bfr(b.y);
    hi[6] = (short)bfr(b.z); hi[7] = (short)bfr(b.w);
}

// ---------------------------------------------------------------------------
// Kernel 1: LDS double-buffered MFMA GEMM — ONE barrier per 64-K chunk.
// R10 ledger: inline conversion costs ~nothing (this beat the cvt_pre split
// by 1.3 us — one less launch, no extra HBM round-trip). ~6 us total.
__global__ __launch_bounds__(256) void gemm_v3(const float* __restrict__ Q,
                                               const float* __restrict__ P,
                                               const float* __restrict__ W1,
                                               const float* __restrict__ b1,
                                               float* __restrict__ A,
                                               float* __restrict__ Bv) {
    __shared__ short XH[2][16 * LST];
    __shared__ short WH[2][64 * LST];
    __shared__ short WL[2][64 * LST];

    int tid  = threadIdx.x;
    int lane = tid & 63;
    int ht   = tid >> 6;
    int m    = blockIdx.x % 5;
    int rt   = blockIdx.x / 5;           // 0..143
    int r0   = rt * 16;
    bool isQ = rt < 128;

    int wrow = tid >> 3;                 // 0..31  (also rows +32)
    int wg8  = (tid & 7) * 8;            // k offset within 64-chunk
    const float* wb  = W1 + (size_t)m * 64 * 1024 + (isQ ? 0 : EMB);
    const float* wp0 = wb + (size_t)wrow * 1024 + wg8;
    const float* wp1 = wb + (size_t)(wrow + 32) * 1024 + wg8;
    bool hasX = tid < 128;
    int xrow  = tid >> 3;                // 0..15 when hasX
    const float* xp = (isQ ? Q + (size_t)(r0 + xrow) * EMB
                           : P + (size_t)(r0 - NQ + xrow) * EMB) + wg8;

    int arix = (lane & 15) * LST + (lane >> 4) * 8;
    int brix = (ht * 16 + (lane & 15)) * LST + (lane >> 4) * 8;

    floatx4 ac = {0, 0, 0, 0};
    float4 w00, w01, w10, w11, x0, x1;

    // prologue: load + convert + store chunk 0 into buf 0
    w00 = *(const float4*)&wp0[0]; w01 = *(const float4*)&wp0[4];
    w10 = *(const float4*)&wp1[0]; w11 = *(const float4*)&wp1[4];
    if (hasX) { x0 = *(const float4*)&xp[0]; x1 = *(const float4*)&xp[4]; }
    {
        short8 hi, lo;
        cvt8(w00, w01, hi, lo);
        *(short8*)&WH[0][wrow * LST + wg8] = hi;
        *(short8*)&WL[0][wrow * LST + wg8] = lo;
        cvt8(w10, w11, hi, lo);
        *(short8*)&WH[0][(wrow + 32) * LST + wg8] = hi;
        *(short8*)&WL[0][(wrow + 32) * LST + wg8] = lo;
        if (hasX) { short8 xh; cvt8hi(x0, x1, xh);
                    *(short8*)&XH[0][xrow * LST + wg8] = xh; }
    }

#pragma unroll 1
    for (int c = 0; c < 8; ++c) {
        int cur = c & 1;
        if (c < 7) {                      // issue loads for c+1 (no wait)
            int k0 = (c + 1) * 64;
            w00 = *(const float4*)&wp0[k0]; w01 = *(const float4*)&wp0[k0 + 4];
            w10 = *(const float4*)&wp1[k0]; w11 = *(const float4*)&wp1[k0 + 4];
            if (hasX) { x0 = *(const float4*)&xp[k0]; x1 = *(const float4*)&xp[k0 + 4]; }
        }
        __syncthreads();                  // buf[cur] writes done; buf[cur^1] readers done

#pragma unroll
        for (int s = 0; s < 2; ++s) {     // two 32-k sub-chunks
            short8 Ah = *(const short8*)&XH[cur][arix + s * 32];
            short8 Bh = *(const short8*)&WH[cur][brix + s * 32];
            short8 Bl = *(const short8*)&WL[cur][brix + s * 32];
            ac = __builtin_amdgcn_mfma_f32_16x16x32_bf16(Ah, Bl, ac, 0, 0, 0);
            ac = __builtin_amdgcn_mfma_f32_16x16x32_bf16(Ah, Bh, ac, 0, 0, 0);
        }

        if (c < 7) {                      // convert (vmcnt wait lands here) + store
            int nb = cur ^ 1;
            short8 hi, lo;
            cvt8(w00, w01, hi, lo);
            *(short8*)&WH[nb][wrow * LST + wg8] = hi;
            *(short8*)&WL[nb][wrow * LST + wg8] = lo;
            cvt8(w10, w11, hi, lo);
            *(short8*)&WH[nb][(wrow + 32) * LST + wg8] = hi;
            *(short8*)&WL[nb][(wrow + 32) * LST + wg8] = lo;
            if (hasX) { short8 xh; cvt8hi(x0, x1, xh);
                        *(short8*)&XH[nb][xrow * LST + wg8] = xh; }
        }
    }

    int col  = lane & 15;                 // h within tile
    int rloc = (lane >> 4) * 4;           // row within tile (+reg)
    int hh   = ht * 16 + col;
    int rr   = r0 + rloc;

    if (isQ) {
        float bb = b1[m * 64 + hh];
        float* dst = &A[((size_t)m * NQ + rr) * HID + hh];
        dst[0 * HID] = ac.x + bb; dst[1 * HID] = ac.y + bb;
        dst[2 * HID] = ac.z + bb; dst[3 * HID] = ac.w + bb;
    } else {
        int p = rr - NQ;
        float* dst = &Bv[(((size_t)(m * 16 + (hh >> 2))) * NP + p) * 4 + (hh & 3)];
        dst[0 * 4] = ac.x; dst[1 * 4] = ac.y; dst[2 * 4] = ac.z; dst[3 * 4] = ac.w;
    }
}

// ---------------------------------------------------------------------------
// Kernel 2: fused relu-ensemble + mean/std/exp — best-measured version
// (R2/R6, ~3.6 us per the R10 ledger; near its 3.2 us pk-VALU floor).
// grid 1024 = 4 p-tiles(64) x 256 q-tiles(8); 4 blocks/CU = 16 waves/CU;
// A in LDS (stride 68, conflict-free); single Bc[16] reg set (coalescer
// dedups the qg duplication — qg in LOW tid bits); pk-fp32 math.
#define AST 68
__global__ __launch_bounds__(256) void fused_main(const float* __restrict__ A,
                                                  const float* __restrict__ Bv,
                                                  const float* __restrict__ W2,
                                                  const float* __restrict__ b2,
                                                  float* __restrict__ out) {
    __shared__ float As[NM][8][AST];          // 10,880 B

    int tid  = threadIdx.x;
    int bp   = (blockIdx.x & 3) * 64;         // p-tile base
    int q0   = (blockIdx.x >> 2) * 8;         // q-tile base
    int p    = tid >> 2;                      // 0..63 within p-tile
    int qg   = tid & 3;                       // 0..3

    // stage A slice: 5 x 8 x 64 floats = 640 float4
    {
        const float4* Ag = (const float4*)A;  // f4 idx (m*NQ+q)*16 + j
        for (int i = tid; i < 640; i += 256) {
            int m = i >> 7, rem = i & 127;
            int qr = rem >> 4, j = rem & 15;
            *(float4*)&As[m][qr][j * 4] =
                Ag[(size_t)m * (NQ * 16) + (size_t)(q0 + qr) * 16 + j];
        }
    }
    __syncthreads();

    const vf4* Bq = (const vf4*)Bv + (bp + p);   // f4 idx (m*16+j)*NP + p

    float s1[2] = {0.f, 0.f}, s2[2] = {0.f, 0.f};

#pragma unroll 1
    for (int m = 0; m < NM; ++m) {
        vf4 Bc[16];
#pragma unroll
        for (int j = 0; j < 16; ++j) Bc[j] = Bq[(m * 16 + j) * NP];

        const float* Wm = W2 + m * HID;           // block-uniform
        float bb = b2[m];

#pragma unroll
        for (int qi = 0; qi < 2; ++qi) {
            const float* Ar = &As[m][qg * 2 + qi][0];
            vf2 acc = {0.f, 0.f};
#pragma unroll
            for (int j = 0; j < 16; ++j) {
                vf2 a0 = *(const vf2*)&Ar[j * 4 + 0];
                vf2 a1 = *(const vf2*)&Ar[j * 4 + 2];
                vf2 w0 = *(const vf2*)&Wm[j * 4 + 0];
                vf2 w1 = *(const vf2*)&Wm[j * 4 + 2];
                vf2 z  = {0.f, 0.f};
                vf2 t0 = __builtin_elementwise_max(a0 + Bc[j].xy, z);
                vf2 t1 = __builtin_elementwise_max(a1 + Bc[j].zw, z);
                acc = t0 * w0 + acc;              // v_pk_fma_f32
                acc = t1 * w1 + acc;
            }
            float x = acc.x + acc.y + bb;
            s1[qi] += x;
            s2[qi] = fmaf(x, x, s2[qi]);
        }
    }

#pragma unroll
    for (int qi = 0; qi < 2; ++qi) {
        float mean = s1[qi] * 0.2f;
        float var  = fmaxf((s2[qi] - s1[qi] * s1[qi] * 0.2f) * 0.25f, 0.f);
        out[(size_t)(q0 + qg * 2 + qi) * NP + bp + p] =
            mean * __expf(-sqrtf(var));
    }
}

// ---------------------------------------------------------------------------
extern "C" void kernel_launch(void* const* d_in, const int* in_sizes, int n_in,
                              void* d_out, int out_size, void* d_ws, size_t ws_size,
                              hipStream_t stream) {
    const float* Q  = (const float*)d_in[0];   // (2048, 512)
    const float* P  = (const float*)d_in[1];   // (256, 512)
    const float* W1 = (const float*)d_in[2];   // (5, 64, 1024)
    const float* b1 = (const float*)d_in[3];   // (5, 64)
    const float* W2 = (const float*)d_in[4];   // (5, 64)
    const float* b2 = (const float*)d_in[5];   // (5,)
    float* out = (float*)d_out;

    char*  ws = (char*)d_ws;
    float* A  = (float*)(ws + A_BY);
    float* B  = (float*)(ws + B_BY);

    gemm_v3<<<720, 256, 0, stream>>>(Q, P, W1, b1, A, B);
    fused_main<<<1024, 256, 0, stream>>>(A, B, W2, b2, out);
}